// Round 1
// baseline (634.438 us; speedup 1.0000x reference)
//
#include <hip/hip_runtime.h>
#include <cfloat>

// Problem constants (reference: B=32, C=256, H=W=64, nh=4, hid=C/4=64, S=40)
#define B_    32
#define C_    256
#define HW_   4096
#define NH_   4
#define HID_  64
#define SSEL_ 40
#define GADD_ 0.0075f   // 0.3 * (1/40): pixel_imp collapses to 1/S exactly

// ---------------------------------------------------------------------------
// K1: per-pixel graph_modulator MLP (256 -> 64 relu -> 4 sigmoid, mean heads)
//     m[b*HW+p]   = 0.7 * mean_h sigmoid(...)
//     imp[b*HW+p] = sum_c |x[b,c,p]|   (scale-invariant ranking key)
// One thread per pixel; lanes cover consecutive pixels -> coalesced reads of
// x[b,c,p] (stride-HW over c per thread, contiguous over lanes).
// ---------------------------------------------------------------------------
__global__ __launch_bounds__(256) void k_mod_imp(
    const float* __restrict__ x,
    const float* __restrict__ w1, const float* __restrict__ b1,
    const float* __restrict__ w2, const float* __restrict__ b2,
    float* __restrict__ m, float* __restrict__ imp)
{
    const int pix = blockIdx.x * 256 + threadIdx.x;   // [0, B*HW)
    const int b = pix >> 12;                          // HW = 4096 = 2^12
    const float* __restrict__ xb = x + ((size_t)b * C_) * HW_ + (pix & (HW_ - 1));

    float acc[HID_];
    #pragma unroll
    for (int j = 0; j < HID_; ++j) acc[j] = b1[j];
    float sabs = 0.f;

    for (int c0 = 0; c0 < C_; c0 += 8) {
        float xv[8];
        #pragma unroll
        for (int cc = 0; cc < 8; ++cc) xv[cc] = xb[(size_t)(c0 + cc) << 12];
        #pragma unroll
        for (int cc = 0; cc < 8; ++cc) sabs += fabsf(xv[cc]);
        #pragma unroll
        for (int j = 0; j < HID_; ++j) {
            const float* __restrict__ wr = w1 + j * C_ + c0;  // uniform -> s_load
            #pragma unroll
            for (int cc = 0; cc < 8; ++cc) acc[j] = fmaf(wr[cc], xv[cc], acc[j]);
        }
    }

    #pragma unroll
    for (int j = 0; j < HID_; ++j) acc[j] = fmaxf(acc[j], 0.f);

    float ssum = 0.f;
    #pragma unroll
    for (int h = 0; h < NH_; ++h) {
        float s = b2[h];
        const float* __restrict__ wr = w2 + h * HID_;
        #pragma unroll
        for (int j = 0; j < HID_; ++j) s = fmaf(wr[j], acc[j], s);
        ssum += 1.f / (1.f + __expf(-s));
    }
    m[pix]   = 0.175f * ssum;   // 0.7 * (1/4) * sum of sigmoids
    imp[pix] = sabs;
}

// ---------------------------------------------------------------------------
// K2: per-batch top-40 extraction; winners get m += 0.3/40.
// One wave (64 lanes) per batch; lane holds 64 values in registers with
// 8-wide cached group maxima. Removal searched only in the group that owns
// the current max (wave-uniform __any branch) -> cheap iterations.
// Exact-duplicate importance values (measure-zero for random fp32 sums)
// would be removed together; acceptable.
// ---------------------------------------------------------------------------
__global__ __launch_bounds__(64) void k_topk(
    const float* __restrict__ imp, float* __restrict__ m)
{
    const int b    = blockIdx.x;
    const int lane = threadIdx.x;
    const float* __restrict__ ib = imp + (size_t)b * HW_;
    float* __restrict__ mb = m + (size_t)b * HW_;

    float v[64];
    #pragma unroll
    for (int i = 0; i < 64; ++i) v[i] = ib[i * 64 + lane];  // pixel = i*64+lane

    float g[8];
    #pragma unroll
    for (int k = 0; k < 8; ++k) {
        float gm = v[8 * k];
        #pragma unroll
        for (int i = 1; i < 8; ++i) gm = fmaxf(gm, v[8 * k + i]);
        g[k] = gm;
    }

    for (int it = 0; it < SSEL_; ++it) {
        float lm = g[0];
        #pragma unroll
        for (int k = 1; k < 8; ++k) lm = fmaxf(lm, g[k]);
        // wave-wide max (all lanes converge to the same value)
        float wm = lm;
        #pragma unroll
        for (int off = 32; off >= 1; off >>= 1)
            wm = fmaxf(wm, __shfl_xor(wm, off, 64));
        // locate + remove + update m; only the owning group's branch is taken
        #pragma unroll
        for (int k = 0; k < 8; ++k) {
            if (__any(g[k] == wm)) {
                int gi = -1;
                #pragma unroll
                for (int i = 0; i < 8; ++i) {
                    if (v[8 * k + i] == wm) {
                        gi = (8 * k + i) * 64 + lane;
                        v[8 * k + i] = -FLT_MAX;
                    }
                }
                float gm = v[8 * k];
                #pragma unroll
                for (int i = 1; i < 8; ++i) gm = fmaxf(gm, v[8 * k + i]);
                g[k] = gm;
                if (gi >= 0) mb[gi] += GADD_;   // unique owner lane, no atomic
            }
        }
    }
}

// ---------------------------------------------------------------------------
// K3: out[b,c,p] = x[b,c,p] * m[b,p]   (float4; m plane is L2/L3-resident)
// ---------------------------------------------------------------------------
__global__ __launch_bounds__(256) void k_apply(
    const float4* __restrict__ x4, const float* __restrict__ m,
    float4* __restrict__ o4)
{
    const size_t i = (size_t)blockIdx.x * 256 + threadIdx.x;  // float4 index
    const size_t flat = i << 2;
    const int b = (int)(flat >> 20);          // C_*HW_ = 2^20
    const int p = (int)(flat & (HW_ - 1));    // multiple of 4 -> aligned float4
    const float4 mv = *(const float4*)(m + ((size_t)b << 12) + p);
    const float4 xv = x4[i];
    float4 r;
    r.x = xv.x * mv.x; r.y = xv.y * mv.y;
    r.z = xv.z * mv.z; r.w = xv.w * mv.w;
    o4[i] = r;
}

extern "C" void kernel_launch(void* const* d_in, const int* in_sizes, int n_in,
                              void* d_out, int out_size, void* d_ws, size_t ws_size,
                              hipStream_t stream)
{
    const float* x  = (const float*)d_in[0];
    const float* w1 = (const float*)d_in[1];  // gm_w1 [64,256]
    const float* b1 = (const float*)d_in[2];  // gm_b1 [64]
    const float* w2 = (const float*)d_in[3];  // gm_w2 [4,64]
    const float* b2 = (const float*)d_in[4];  // gm_b2 [4]
    // d_in[5..9] (qkv_w, ge_*) provably do not affect the output: softmax rows
    // mean to 1/S regardless of scores.

    float* m   = (float*)d_ws;                 // B*HW floats (512 KB)
    float* imp = m + (size_t)B_ * HW_;         // B*HW floats (512 KB)
    float* out = (float*)d_out;

    k_mod_imp<<<dim3((B_ * HW_) / 256), dim3(256), 0, stream>>>(x, w1, b1, w2, b2, m, imp);
    k_topk<<<dim3(B_), dim3(64), 0, stream>>>(imp, m);
    const int n4 = (B_ * C_ * HW_) / 4;
    k_apply<<<dim3(n4 / 256), dim3(256), 0, stream>>>((const float4*)x, m, (float4*)out);
}

// Round 2
// 328.413 us; speedup vs baseline: 1.9318x; 1.9318x over previous
//
#include <hip/hip_runtime.h>
#include <cfloat>

// Problem constants (reference: B=32, C=256, H=W=64, nh=4, hid=C/4=64, S=40)
#define B_    32
#define C_    256
#define HW_   4096
#define NH_   4
#define HID_  64
#define SSEL_ 40
#define GADD_ 0.0075f   // 0.3 * (1/40): pixel_imp collapses to 1/S exactly

// ---------------------------------------------------------------------------
// K1 v2: LDS-tiled fp32 GEMM formulation of the graph_modulator MLP.
//   H1[64][px] = relu(W1 @ X_b + b1); m = 0.175 * sum_h sigmoid(W2 @ H1 + b2)
// Block: 256 threads, tile = 64 hid x 128 px, K-step = 32 channels.
// Thread (pxg = t&31, hidg = t>>5) owns acc[8 hid][4 px] = 32 VGPRs.
// v1 post-mortem: acc[64] per thread spilled to scratch (VGPR_Count=48),
// 397 us at 7% useful-FMA. This version caps per-thread arrays at 32.
// Importance sum|x| is folded into staging: thread t's staged float4s all
// cover px-group (t&31), channels {t>>5 + 8m}, so per-thread partials are
// complete over disjoint channel sets -> small LDS reduction.
// ---------------------------------------------------------------------------
__global__ __launch_bounds__(256) void k_mlp(
    const float* __restrict__ x,
    const float* __restrict__ w1, const float* __restrict__ b1,
    const float* __restrict__ w2, const float* __restrict__ b2,
    float* __restrict__ m, float* __restrict__ imp)
{
    __shared__ float XT[32 * 128];   // [k][px]  16 KB
    __shared__ float WT[32 * 64];    // [k][hid]  8 KB (transposed W1 slab)
    __shared__ float H1[64 * 128];   // [hid][px] 32 KB
    __shared__ float SAB[256 * 4];   //           4 KB  (importance partials)

    const int t  = threadIdx.x;
    const int b  = blockIdx.x >> 5;          // 32 px-tiles per batch
    const int p0 = (blockIdx.x & 31) * 128;
    const float* __restrict__ xb = x + ((size_t)b << 20) + p0;  // + b*C*HW

    const int pxg  = t & 31;   // owns px p0 + pxg*4 .. +3
    const int hidg = t >> 5;   // owns hid hidg*8 .. +7

    float acc[8][4];
    #pragma unroll
    for (int j = 0; j < 8; ++j) {
        const float bj = b1[hidg * 8 + j];
        #pragma unroll
        for (int p = 0; p < 4; ++p) acc[j][p] = bj;
    }
    float4 sa = make_float4(0.f, 0.f, 0.f, 0.f);

    for (int kk = 0; kk < 8; ++kk) {
        const int c0 = kk * 32;
        if (kk) __syncthreads();             // protect LDS before overwrite
        // stage XT[k][px]: 4096 floats as 1024 float4, 4 per thread.
        // q = t + i*256 -> k-row = q>>5, px-group = q&31 == t&31 (coalesced).
        #pragma unroll
        for (int i = 0; i < 4; ++i) {
            const int q   = t + i * 256;
            const int row = q >> 5;
            const float4 v = *(const float4*)(xb + (size_t)(c0 + row) * HW_ + pxg * 4);
            *(float4*)(XT + row * 128 + pxg * 4) = v;
            sa.x += fabsf(v.x); sa.y += fabsf(v.y);
            sa.z += fabsf(v.z); sa.w += fabsf(v.w);
        }
        // stage WT[k][hid] (transposed): 2048 floats, 8 per thread.
        // Uncoalesced (stride-256 gather) but w1 is 64 KB -> L2-resident.
        #pragma unroll
        for (int i = 0; i < 8; ++i) {
            const int q = t + i * 256;
            const int k = q >> 6, j = q & 63;
            WT[k * 64 + j] = w1[j * C_ + c0 + k];
        }
        __syncthreads();
        #pragma unroll
        for (int k = 0; k < 32; ++k) {
            const float4 xv = *(const float4*)(XT + k * 128 + pxg * 4);
            const float4 wa = *(const float4*)(WT + k * 64 + hidg * 8);
            const float4 wb = *(const float4*)(WT + k * 64 + hidg * 8 + 4);
            const float xr[4] = {xv.x, xv.y, xv.z, xv.w};
            const float wr[8] = {wa.x, wa.y, wa.z, wa.w, wb.x, wb.y, wb.z, wb.w};
            #pragma unroll
            for (int j = 0; j < 8; ++j)
                #pragma unroll
                for (int p = 0; p < 4; ++p)
                    acc[j][p] = fmaf(wr[j], xr[p], acc[j][p]);
        }
    }

    // relu -> H1 tile in LDS
    #pragma unroll
    for (int j = 0; j < 8; ++j) {
        float4 hv;
        hv.x = fmaxf(acc[j][0], 0.f);
        hv.y = fmaxf(acc[j][1], 0.f);
        hv.z = fmaxf(acc[j][2], 0.f);
        hv.w = fmaxf(acc[j][3], 0.f);
        *(float4*)(H1 + (hidg * 8 + j) * 128 + pxg * 4) = hv;
    }
    *(float4*)(SAB + t * 4) = sa;
    __syncthreads();

    // importance: reduce the 8 channel-groups per px-group
    if (t < 32) {
        float4 s = make_float4(0.f, 0.f, 0.f, 0.f);
        #pragma unroll
        for (int g = 0; g < 8; ++g) {
            const float4 v = *(const float4*)(SAB + (g * 32 + t) * 4);
            s.x += v.x; s.y += v.y; s.z += v.z; s.w += v.w;
        }
        *(float4*)(imp + ((size_t)b << 12) + p0 + t * 4) = s;
    }
    // layer 2: 64 -> 4 heads + sigmoid, 128 threads (1 px each)
    if (t < 128) {
        const int px = t;
        float s0 = b2[0], s1 = b2[1], s2 = b2[2], s3 = b2[3];
        #pragma unroll 8
        for (int j = 0; j < 64; ++j) {
            const float h = H1[j * 128 + px];
            s0 = fmaf(w2[0 * HID_ + j], h, s0);
            s1 = fmaf(w2[1 * HID_ + j], h, s1);
            s2 = fmaf(w2[2 * HID_ + j], h, s2);
            s3 = fmaf(w2[3 * HID_ + j], h, s3);
        }
        const float ssum = 1.f / (1.f + __expf(-s0)) + 1.f / (1.f + __expf(-s1))
                         + 1.f / (1.f + __expf(-s2)) + 1.f / (1.f + __expf(-s3));
        m[((size_t)b << 12) + p0 + px] = 0.175f * ssum;
    }
}

// ---------------------------------------------------------------------------
// K2: per-batch top-40 extraction; winners get m += 0.3/40. (unchanged)
// ---------------------------------------------------------------------------
__global__ __launch_bounds__(64) void k_topk(
    const float* __restrict__ imp, float* __restrict__ m)
{
    const int b    = blockIdx.x;
    const int lane = threadIdx.x;
    const float* __restrict__ ib = imp + (size_t)b * HW_;
    float* __restrict__ mb = m + (size_t)b * HW_;

    float v[64];
    #pragma unroll
    for (int i = 0; i < 64; ++i) v[i] = ib[i * 64 + lane];

    float g[8];
    #pragma unroll
    for (int k = 0; k < 8; ++k) {
        float gm = v[8 * k];
        #pragma unroll
        for (int i = 1; i < 8; ++i) gm = fmaxf(gm, v[8 * k + i]);
        g[k] = gm;
    }

    for (int it = 0; it < SSEL_; ++it) {
        float lm = g[0];
        #pragma unroll
        for (int k = 1; k < 8; ++k) lm = fmaxf(lm, g[k]);
        float wm = lm;
        #pragma unroll
        for (int off = 32; off >= 1; off >>= 1)
            wm = fmaxf(wm, __shfl_xor(wm, off, 64));
        #pragma unroll
        for (int k = 0; k < 8; ++k) {
            if (__any(g[k] == wm)) {
                int gi = -1;
                #pragma unroll
                for (int i = 0; i < 8; ++i) {
                    if (v[8 * k + i] == wm) {
                        gi = (8 * k + i) * 64 + lane;
                        v[8 * k + i] = -FLT_MAX;
                    }
                }
                float gm = v[8 * k];
                #pragma unroll
                for (int i = 1; i < 8; ++i) gm = fmaxf(gm, v[8 * k + i]);
                g[k] = gm;
                if (gi >= 0) mb[gi] += GADD_;
            }
        }
    }
}

// ---------------------------------------------------------------------------
// K3: out[b,c,p] = x[b,c,p] * m[b,p]   (float4; m plane L2/L3-resident)
// ---------------------------------------------------------------------------
__global__ __launch_bounds__(256) void k_apply(
    const float4* __restrict__ x4, const float* __restrict__ m,
    float4* __restrict__ o4)
{
    const size_t i = (size_t)blockIdx.x * 256 + threadIdx.x;
    const size_t flat = i << 2;
    const int b = (int)(flat >> 20);          // C_*HW_ = 2^20
    const int p = (int)(flat & (HW_ - 1));
    const float4 mv = *(const float4*)(m + ((size_t)b << 12) + p);
    const float4 xv = x4[i];
    float4 r;
    r.x = xv.x * mv.x; r.y = xv.y * mv.y;
    r.z = xv.z * mv.z; r.w = xv.w * mv.w;
    o4[i] = r;
}

extern "C" void kernel_launch(void* const* d_in, const int* in_sizes, int n_in,
                              void* d_out, int out_size, void* d_ws, size_t ws_size,
                              hipStream_t stream)
{
    const float* x  = (const float*)d_in[0];
    const float* w1 = (const float*)d_in[1];  // gm_w1 [64,256]
    const float* b1 = (const float*)d_in[2];  // gm_b1 [64]
    const float* w2 = (const float*)d_in[3];  // gm_w2 [4,64]
    const float* b2 = (const float*)d_in[4];  // gm_b2 [4]
    // d_in[5..9] (qkv_w, ge_*) provably do not affect the output: softmax rows
    // mean to 1/S regardless of scores, so pixel_imp == 1/40 exactly.

    float* m   = (float*)d_ws;                 // B*HW floats (512 KB)
    float* imp = m + (size_t)B_ * HW_;         // B*HW floats (512 KB)
    float* out = (float*)d_out;

    k_mlp<<<dim3(B_ * (HW_ / 128)), dim3(256), 0, stream>>>(x, w1, b1, w2, b2, m, imp);
    k_topk<<<dim3(B_), dim3(64), 0, stream>>>(imp, m);
    const int n4 = (B_ * C_ * HW_) / 4;
    k_apply<<<dim3(n4 / 256), dim3(256), 0, stream>>>((const float4*)x, m, (float4*)out);
}